// Round 2
// baseline (28.747 us; speedup 1.0000x reference)
//
#include <hip/hip_runtime.h>

#define B 4
#define CIN 64
#define H 32
#define W 32
#define KSZ 3
#define PADW 1
#define OC 64
#define LMAX 144
#define HP (H + 2*PADW)          // 34
#define WP (W + 2*PADW)          // 34
#define HOUT 32
#define WOUT 32
#define NPIX (HOUT*WOUT)         // 1024
#define CHHALF 32                // channels staged per phase
#define CHANEL (HP*WP)           // 1156 floats per padded channel
#define HALFSZ (CHHALF*CHANEL)   // 36992 floats = 147,968 B LDS

// Fused kernel: one block per (b,o). Stage half the padded image (f32) in
// LDS, gather the taps belonging to that half (uniform scalar filter),
// then restage the other half and gather the rest. No workspace, 1 dispatch.
__global__ __launch_bounds__(1024, 1) void reconv_fused(
    const float* __restrict__ images,
    const int* __restrict__ tap_idx, const float* __restrict__ tap_w,
    const int* __restrict__ bias_index, const float* __restrict__ bias_value,
    float* __restrict__ out) {
    __shared__ float s_img[HALFSZ];            // 147,968 B

    const int bo = blockIdx.x;
    const int b = bo >> 6;                     // / OC
    const int o = bo & (OC - 1);
    const int t = threadIdx.x;
    const int h = t >> 5, w = t & 31;
    const int pixoff = h * WP + w;             // output pixel offset in padded coords

    // Zero whole LDS half-image once. Borders stay zero across both phases;
    // interior is fully overwritten by each phase's staging.
    for (int i = t; i < HALFSZ; i += 1024) s_img[i] = 0.f;

    // bias: general scatter-add semantics, all-uniform scalar work
    float bias = 0.f;
    for (int i = 0; i < OC; ++i)
        bias += (bias_index[i] == o) ? bias_value[i] : 0.f;

    const int tbase = o * LMAX;
    float acc = 0.f;

    for (int p = 0; p < 2; ++p) {
        __syncthreads();                       // LDS ready for (re)staging
        // Stage channels [p*32, p*32+32): coalesced global loads,
        // conflict-free LDS writes (lane stride = 4 B).
        const float* gsrc = images + ((size_t)(b * CIN + p * CHHALF)) * (H * W);
        #pragma unroll
        for (int i = 0; i < CHHALF; ++i) {
            float v = gsrc[i * (H * W) + t];
            s_img[i * CHANEL + (h + 1) * WP + (w + 1)] = v;
        }
        __syncthreads();

        // Gather taps whose channel lies in this half. idx/wgt are at
        // uniform addresses -> s_load; the range test is a scalar branch.
        const int lo = p * HALFSZ;
        #pragma unroll 8
        for (int l = 0; l < LMAX; ++l) {
            int idx = tap_idx[tbase + l];
            unsigned rel = (unsigned)(idx - lo);
            if (rel < (unsigned)HALFSZ) {
                float wgt = tap_w[tbase + l];
                acc += wgt * s_img[rel + pixoff];   // in-bounds by construction
            }
        }
    }

    out[(size_t)bo * NPIX + t] = acc + bias;
}

extern "C" void kernel_launch(void* const* d_in, const int* in_sizes, int n_in,
                              void* d_out, int out_size, void* d_ws, size_t ws_size,
                              hipStream_t stream) {
    const float* images     = (const float*)d_in[0];
    const int*   tap_idx    = (const int*)d_in[1];
    const float* tap_w      = (const float*)d_in[2];
    const int*   bias_index = (const int*)d_in[3];
    const float* bias_value = (const float*)d_in[4];
    float* out = (float*)d_out;

    reconv_fused<<<B * OC, 1024, 0, stream>>>(images, tap_idx, tap_w,
                                              bias_index, bias_value, out);
}

// Round 3
// 16.916 us; speedup vs baseline: 1.6994x; 1.6994x over previous
//
#include <hip/hip_runtime.h>
#include <hip/hip_fp16.h>

#define B 4
#define CIN 64
#define H 32
#define W 32
#define OC 64
#define LMAX 144
#define HP 34
#define WP 34
#define NPIX 1024
#define RSTR 36                        // padded row stride in f16 elems
#define CSTR (HP*RSTR)                 // 1224 elems per channel
#define GUARD 4                        // zero guard elems (keeps 8B alignment)
#define IMG_ELEMS (GUARD + CIN*CSTR)   // 78,340
#define IMG_BYTES (IMG_ELEMS*2)        // 156,680 (mult of 8)

// Single fused kernel. One block per (b,o). Full padded image for batch b
// resident in LDS as f16 (row stride 36, physical col = logical col - 1 with
// a zero guard so kw-1+w==-1 underflows into an always-zero slot -> no
// per-lane bounds checks). Each thread owns 2 pixels: rows h0 and h0+16,
// col w -- this makes each gather instruction's lanes span rows 1 apart
// (18 dwords at stride 36) -> conflict-free LDS banks.
__global__ __launch_bounds__(512, 1) void reconv_lds(
    const float* __restrict__ images,
    const int* __restrict__ tap_idx, const float* __restrict__ tap_w,
    const int* __restrict__ bias_index, const float* __restrict__ bias_value,
    float* __restrict__ out)
{
    __shared__ ushort s_img[IMG_ELEMS];
    __shared__ int2 s_tap[LMAX];       // .x = tap byte offset, .y = weight bits

    const int bo = blockIdx.x;
    const int b = bo >> 6;             // / OC
    const int o = bo & (OC - 1);
    const int t = threadIdx.x;
    const int w = t & 31;
    const int h0 = t >> 5;             // 0..15; thread owns rows h0, h0+16

    // Phase 0: zero whole image LDS (pads + guard + interior).
    for (int i = t; i < IMG_BYTES / 8; i += 512)
        ((unsigned long long*)s_img)[i] = 0ull;

    // Tap decomposition: idx -> (c,kh,kw) -> byte offset in LDS layout.
    if (t < LMAX) {
        int idx = tap_idx[o * LMAX + t];
        int c = idx / (HP * WP);
        int rem = idx - c * (HP * WP);
        int kh = rem / WP;
        int kw = rem - kh * WP;
        int elem = GUARD + c * CSTR + kh * RSTR + (kw - 1);   // physical col = logical-1
        int2 v;
        v.x = elem * 2;
        v.y = __float_as_int(tap_w[o * LMAX + t]);
        s_tap[t] = v;
    }

    // Bias: general scatter-add semantics; all-scalar uniform work.
    float bias = 0.f;
    for (int i = 0; i < OC; ++i)
        bias += (bias_index[i] == o) ? bias_value[i] : 0.f;

    __syncthreads();                   // zero + taps complete

    // Phase 1: stage image(b) f32 -> f16 into LDS interior.
    // 16384 float4s; thread does 32 of them, fully coalesced.
    const float4* img4 = (const float4*)images + (size_t)b * (CIN * H * W / 4);
    #pragma unroll 4
    for (int i = 0; i < 32; ++i) {
        int f = i * 512 + t;
        float4 v = img4[f];
        int c = f >> 8;                // 256 float4 per channel
        int p4 = f & 255;
        int r = p4 >> 3;               // image row 0..31
        int cc = (p4 & 7) << 2;        // image col (mult of 4)
        int e = GUARD + c * CSTR + (r + 1) * RSTR + cc;   // physical col = (cc+1)-1
        ushort4 u;
        u.x = __half_as_ushort(__float2half(v.x));
        u.y = __half_as_ushort(__float2half(v.y));
        u.z = __half_as_ushort(__float2half(v.z));
        u.w = __half_as_ushort(__float2half(v.w));
        *(ushort4*)&s_img[e] = u;      // e % 4 == 0 -> 8B aligned
    }
    __syncthreads();

    // Phase 2: gather. Branchless: pads/guard are zero in LDS.
    const char* sbase = (const char*)s_img;
    const int pxo = (h0 * RSTR + w) * 2;
    float a0 = 0.f, a1 = 0.f;
    #pragma unroll 8
    for (int l = 0; l < LMAX; ++l) {
        int2 tp = s_tap[l];            // ds_read_b64 broadcast
        int boff = pxo + tp.x;
        float wgt = __int_as_float(tp.y);
        __half x0 = *(const __half*)(sbase + boff);
        __half x1 = *(const __half*)(sbase + boff + 16 * RSTR * 2);
        a0 += wgt * __half2float(x0);
        a1 += wgt * __half2float(x1);
    }

    float* op = out + (size_t)bo * NPIX;
    op[h0 * 32 + w] = a0 + bias;
    op[(h0 + 16) * 32 + w] = a1 + bias;
}

extern "C" void kernel_launch(void* const* d_in, const int* in_sizes, int n_in,
                              void* d_out, int out_size, void* d_ws, size_t ws_size,
                              hipStream_t stream) {
    const float* images     = (const float*)d_in[0];
    const int*   tap_idx    = (const int*)d_in[1];
    const float* tap_w      = (const float*)d_in[2];
    const int*   bias_index = (const int*)d_in[3];
    const float* bias_value = (const float*)d_in[4];
    float* out = (float*)d_out;

    reconv_lds<<<B * OC, 512, 0, stream>>>(images, tap_idx, tap_w,
                                           bias_index, bias_value, out);
}